// Round 21
// baseline (345.116 us; speedup 1.0000x reference)
//
#include <hip/hip_runtime.h>
#include <hip/hip_bf16.h>
#include <math.h>

typedef __hip_bfloat16 bf16;
typedef __attribute__((ext_vector_type(8))) short short8;
typedef __attribute__((ext_vector_type(4))) short short4v;
typedef __attribute__((ext_vector_type(4))) float f32x4;

#define SEQ 3072
#define HID 1152
#define NHEAD 16
#define HD 72
#define HDP 96
#define MLPD 4304
#define MLPP 4352

__device__ __forceinline__ void async_lds16(void* lds, const void* g) {
  __builtin_amdgcn_global_load_lds((const __attribute__((address_space(1))) void*)g,
                                   (__attribute__((address_space(3))) void*)lds,
                                   16, 0, 0);
}

// one v_cvt_pk_bf16_f32: a -> low16, b -> high16 (RNE)
__device__ __forceinline__ unsigned cvt_pk2(float a, float b) {
  unsigned r;
  asm("v_cvt_pk_bf16_f32 %0, %1, %2" : "=v"(r) : "v"(a), "v"(b));
  return r;
}

// raw v_exp_f32: 2^x
__device__ __forceinline__ float exp2a(float x) {
  float r;
  asm("v_exp_f32 %0, %1" : "=v"(r) : "v"(x));
  return r;
}

// bf16 pair (packed in u32) -> two floats, bit-ops only
__device__ __forceinline__ float bflo(unsigned u) { return __uint_as_float(u << 16); }
__device__ __forceinline__ float bfhi(unsigned u) { return __uint_as_float(u & 0xffff0000u); }

// ---------------- prep: LN0 (blocks < SEQ) + weight casts + q/k/v pads (rest) ----------------
__global__ __launch_bounds__(256) void prep_k(const float* __restrict__ hidden,
                                              const float* __restrict__ ln0g,
                                              const float* __restrict__ ln0b,
                                              const float* __restrict__ wqkv,
                                              const float* __restrict__ wo,
                                              const float* __restrict__ w0,
                                              const float* __restrict__ w1,
                                              bf16* __restrict__ ln0_o,
                                              unsigned* __restrict__ wqkv_o,
                                              unsigned* __restrict__ wo_o,
                                              unsigned* __restrict__ fc0_o,
                                              unsigned* __restrict__ fc1_o,
                                              bf16* __restrict__ qp,
                                              bf16* __restrict__ kp,
                                              bf16* __restrict__ vt) {
  if (blockIdx.x < SEQ) {
    // ---- LN0 row ----
    int row = blockIdx.x;
    const float4* xr = (const float4*)(hidden + (size_t)row * HID);
    float sum = 0.f, sq = 0.f;
    for (int c = threadIdx.x; c < HID / 4; c += 256) {
      float4 u = xr[c];
      sum += u.x + u.y + u.z + u.w;
      sq += u.x * u.x + u.y * u.y + u.z * u.z + u.w * u.w;
    }
#pragma unroll
    for (int off = 32; off > 0; off >>= 1) {
      sum += __shfl_down(sum, off, 64);
      sq += __shfl_down(sq, off, 64);
    }
    __shared__ float red[8];
    int wv = threadIdx.x >> 6;
    if ((threadIdx.x & 63) == 0) { red[wv] = sum; red[4 + wv] = sq; }
    __syncthreads();
    if (threadIdx.x == 0) {
      red[0] = red[0] + red[1] + red[2] + red[3];
      red[4] = red[4] + red[5] + red[6] + red[7];
    }
    __syncthreads();
    float mu = red[0] * (1.f / HID);
    float var = red[4] * (1.f / HID) - mu * mu;
    float inv = rsqrtf(var + 1e-5f);
    uint2* o4 = (uint2*)(ln0_o + (size_t)row * HID);
    const float4* g4 = (const float4*)ln0g;
    const float4* b4 = (const float4*)ln0b;
    for (int c = threadIdx.x; c < HID / 4; c += 256) {
      float4 u = xr[c], gg = g4[c], bb = b4[c];
      o4[c] = make_uint2(cvt_pk2((u.x - mu) * inv * gg.x + bb.x, (u.y - mu) * inv * gg.y + bb.y),
                         cvt_pk2((u.z - mu) * inv * gg.z + bb.z, (u.w - mu) * inv * gg.w + bb.w));
    }
    return;
  }
  // ---- weight casts + pads (grid-stride over the remaining blocks) ----
  const int n0 = 3 * HID * HID / 4;
  const int n1 = HID * HID / 4;
  const int n2 = MLPP * HID / 4;
  const int n3 = HID * MLPP / 4;
  const int n4 = NHEAD * SEQ * 6;   // qp pads: d 72..95 = 6 uint2 per (h,s)
  const int n5 = n4;                // kp pads
  const int n6 = NHEAD * 24 * 768;  // vt rows d=72..95: 768 uint2 per (h,d)
  const int total = n0 + n1 + n2 + n3 + n4 + n5 + n6;
  int nb = gridDim.x - SEQ;
  int stride = nb * blockDim.x;
  for (int i = (blockIdx.x - SEQ) * blockDim.x + threadIdx.x; i < total; i += stride) {
    if (i < n0) {
      float4 u = ((const float4*)wqkv)[i];
      ((uint2*)wqkv_o)[i] = make_uint2(cvt_pk2(u.x, u.y), cvt_pk2(u.z, u.w));
    } else if (i < n0 + n1) {
      int k = i - n0;
      float4 u = ((const float4*)wo)[k];
      ((uint2*)wo_o)[k] = make_uint2(cvt_pk2(u.x, u.y), cvt_pk2(u.z, u.w));
    } else if (i < n0 + n1 + n2) {
      int k = i - n0 - n1;
      int r = k / (HID / 4);
      uint2 w = make_uint2(0u, 0u);
      if (r < MLPD) {
        float4 u = ((const float4*)w0)[k];
        w = make_uint2(cvt_pk2(u.x, u.y), cvt_pk2(u.z, u.w));
      }
      ((uint2*)fc0_o)[k] = w;
    } else if (i < n0 + n1 + n2 + n3) {
      int k = i - n0 - n1 - n2;
      int r = k / (MLPP / 4), c4 = k - r * (MLPP / 4);
      uint2 w = make_uint2(0u, 0u);
      if (c4 < MLPD / 4) {
        float4 u = ((const float4*)w1)[r * (MLPD / 4) + c4];
        w = make_uint2(cvt_pk2(u.x, u.y), cvt_pk2(u.z, u.w));
      }
      ((uint2*)fc1_o)[k] = w;
    } else if (i < n0 + n1 + n2 + n3 + n4) {
      int k = i - (n0 + n1 + n2 + n3);
      int hs = k / 6, u = k - hs * 6;
      ((uint2*)(qp + (size_t)hs * HDP + 72))[u] = make_uint2(0u, 0u);
    } else if (i < n0 + n1 + n2 + n3 + n4 + n5) {
      int k = i - (n0 + n1 + n2 + n3 + n4);
      int hs = k / 6, u = k - hs * 6;
      ((uint2*)(kp + (size_t)hs * HDP + 72))[u] = make_uint2(0u, 0u);
    } else {
      int k = i - (n0 + n1 + n2 + n3 + n4 + n5);
      int hd = k / 768, s4 = k - hd * 768;
      int d = 72 + (hd % 24);
      int hh = hd / 24;
      unsigned val = (d == 72) ? 0x3F803F80u : 0u;  // bf16 1.0 pair (ones-row for l)
      ((uint2*)(vt + ((size_t)hh * HDP + d) * SEQ))[s4] = make_uint2(val, val);
    }
  }
}

// ---------------- layernorm (bf16 in -> bf16 out) ----------------
__global__ __launch_bounds__(256) void ln_bf_k(const bf16* __restrict__ x,
                                               const float* __restrict__ g,
                                               const float* __restrict__ b,
                                               bf16* __restrict__ o) {
  int row = blockIdx.x;
  const uint2* xr = (const uint2*)(x + (size_t)row * HID);
  float sum = 0.f, sq = 0.f;
  for (int c = threadIdx.x; c < HID / 4; c += 256) {
    uint2 u = xr[c];
    float a0 = bflo(u.x), a1 = bfhi(u.x), a2 = bflo(u.y), a3 = bfhi(u.y);
    sum += (a0 + a1) + (a2 + a3);
    sq += (a0 * a0 + a1 * a1) + (a2 * a2 + a3 * a3);
  }
#pragma unroll
  for (int off = 32; off > 0; off >>= 1) {
    sum += __shfl_down(sum, off, 64);
    sq += __shfl_down(sq, off, 64);
  }
  __shared__ float red[8];
  int wv = threadIdx.x >> 6;
  if ((threadIdx.x & 63) == 0) { red[wv] = sum; red[4 + wv] = sq; }
  __syncthreads();
  if (threadIdx.x == 0) {
    red[0] = red[0] + red[1] + red[2] + red[3];
    red[4] = red[4] + red[5] + red[6] + red[7];
  }
  __syncthreads();
  float mu = red[0] * (1.f / HID);
  float var = red[4] * (1.f / HID) - mu * mu;
  float inv = rsqrtf(var + 1e-5f);
  uint2* o4 = (uint2*)(o + (size_t)row * HID);
  const float4* g4 = (const float4*)g;
  const float4* b4 = (const float4*)b;
  for (int c = threadIdx.x; c < HID / 4; c += 256) {
    uint2 u = xr[c];
    float4 gg = g4[c], bb = b4[c];
    float a0 = bflo(u.x), a1 = bfhi(u.x), a2 = bflo(u.y), a3 = bfhi(u.y);
    o4[c] = make_uint2(cvt_pk2((a0 - mu) * inv * gg.x + bb.x, (a1 - mu) * inv * gg.y + bb.y),
                       cvt_pk2((a2 - mu) * inv * gg.z + bb.z, (a3 - mu) * inv * gg.w + bb.w));
  }
}

// ---------------- GEMM: C[M][N] = A[M][K] @ Bt[N][K]^T  (+ epilogue) ----------------
// 3 LDS buffers, depth-2 prefetch, counted vmcnt, bijective XCD swizzle,
// LDS chunk XOR-swizzle. BN=64: 36KB LDS -> 4 blocks/CU (residency lever,
// proven on WO/FC1/FC0 — R12/R19).
// EPI 1: +bias+resf -> bf16 (WO+hidden)   2: +bias,gelu -> bf16   3: +bias+resb -> fp32
template <int EPI, int BN>
__global__ __launch_bounds__(256) void gemm_bf16(const bf16* __restrict__ A,
                                                 const bf16* __restrict__ Bt,
                                                 const float* __restrict__ bias, int nbias,
                                                 const float* __restrict__ resf,
                                                 const bf16* __restrict__ resb,
                                                 float* __restrict__ outf,
                                                 bf16* __restrict__ outb,
                                                 int M, int N, int K) {
  constexpr int NFR = (BN == 128) ? 4 : 2;
  __shared__ bf16 As[3][128 * 32];
  __shared__ bf16 Bs[3][BN * 32];
  const int t = threadIdx.x;
  const int l = t & 63;
  const int w = t >> 6;
  const int wr = w >> 1, wc = w & 1;
  const int lrow = l & 15;
  const int lks = (((l >> 4) ^ ((lrow >> 1) & 3)) & 3) * 8;
  const int wg = (blockIdx.x & 7) * (gridDim.x >> 3) + (blockIdx.x >> 3);
  const int gyt = M >> 7;
  const int xt = wg / gyt;
  const int yt = wg - xt * gyt;
  const int m0 = yt * 128;
  const int n0 = xt * BN;
  const int arow = t >> 2;
  const int ach = (((t & 3) ^ ((t >> 3) & 3)) & 3) * 8;

  const bf16* pa0 = &A[(size_t)(m0 + arow) * K + ach];
  const bf16* pa1 = &A[(size_t)(m0 + arow + 64) * K + ach];
  const bf16* pb0 = &Bt[(size_t)(n0 + arow) * K + ach];
  const bf16* pb1 = (BN == 128) ? &Bt[(size_t)(n0 + arow + 64) * K + ach] : pb0;
  auto STAGE = [&](int buf, int kt) {
    size_t off = (size_t)kt * 32;
    async_lds16(&As[buf][t * 8], pa0 + off);
    async_lds16(&As[buf][(256 + t) * 8], pa1 + off);
    async_lds16(&Bs[buf][t * 8], pb0 + off);
    if constexpr (BN == 128) async_lds16(&Bs[buf][(256 + t) * 8], pb1 + off);
  };

  f32x4 acc[4][NFR] = {};
  const int nkt = K >> 5;
  STAGE(0, 0);
  STAGE(1, 1);
  int bcur = 0;
  for (int kt = 0; kt < nkt; ++kt) {
    if (kt + 1 < nkt) {
      if constexpr (BN == 128)
        asm volatile("s_waitcnt vmcnt(4)" ::: "memory");
      else
        asm volatile("s_waitcnt vmcnt(3)" ::: "memory");
    } else {
      asm volatile("s_waitcnt vmcnt(0)" ::: "memory");
    }
    __builtin_amdgcn_s_barrier();
    int bn2 = bcur + 2;
    if (bn2 >= 3) bn2 -= 3;
    if (kt + 2 < nkt) STAGE(bn2, kt + 2);

    short8 af[4], bfr[NFR];
#pragma unroll
    for (int i = 0; i < 4; ++i)
      af[i] = *(const short8*)&As[bcur][(wr * 64 + i * 16 + lrow) * 32 + lks];
#pragma unroll
    for (int j = 0; j < NFR; ++j)
      bfr[j] = *(const short8*)&Bs[bcur][(wc * (BN >> 1) + j * 16 + lrow) * 32 + lks];
    __builtin_amdgcn_s_setprio(1);
#pragma unroll
    for (int i = 0; i < 4; ++i)
#pragma unroll
      for (int j = 0; j < NFR; ++j)
        acc[i][j] = __builtin_amdgcn_mfma_f32_16x16x32_bf16(af[i], bfr[j], acc[i][j], 0, 0, 0);
    __builtin_amdgcn_s_setprio(0);
    ++bcur;
    if (bcur == 3) bcur = 0;
  }

#pragma unroll
  for (int i = 0; i < 4; ++i) {
    int rowb = m0 + wr * 64 + i * 16 + (l >> 4) * 4;
#pragma unroll
    for (int j = 0; j < NFR; ++j) {
      int col = n0 + wc * (BN >> 1) + j * 16 + lrow;
      float bv = (col < nbias) ? bias[col] : 0.f;
#pragma unroll
      for (int r2 = 0; r2 < 4; ++r2) {
        size_t idx = (size_t)(rowb + r2) * N + col;
        float v = acc[i][j][r2] + bv;
        if (EPI == 1) {
          outb[idx] = __float2bfloat16(v + resf[idx]);
        } else if (EPI == 2) {
          float u = 0.7978845608028654f * (v + 0.044715f * v * v * v);
          u = fminf(fmaxf(u, -15.f), 15.f);
          float tt = __expf(2.f * u);
          outb[idx] = __float2bfloat16(v * tt / (tt + 1.f));
        } else {
          outf[idx] = v + __bfloat162float(resb[idx]);
        }
      }
    }
  }
}

// ---------------- QKV GEMM with fused rope/split epilogue (BN=64) ----------------
// Same pipeline as gemm_bf16<*,64> (36KB LDS -> 4 blocks/CU, grid 1296).
// Epilogue applies rope to q/k (pair via shfl_xor(1): col parity == lane
// parity, pairs never cross the 16-lane group), scales q by
// (1/sqrt(72))*log2(e), and writes v TRANSPOSED (vt[h][d][s], packed 4-s
// uint2). Region boundaries (1152, 2304) are multiples of 64 so no tile
// straddles regions.
__global__ __launch_bounds__(256) void gemm_qkv(const bf16* __restrict__ A,
                                                const bf16* __restrict__ Bt,
                                                const float* __restrict__ bias,
                                                const float* __restrict__ cosb,
                                                const float* __restrict__ sinb,
                                                bf16* __restrict__ qp,
                                                bf16* __restrict__ kp,
                                                bf16* __restrict__ vt) {
  constexpr int BN = 64;
  const int M = SEQ, K = HID;
  __shared__ bf16 As[3][128 * 32];
  __shared__ bf16 Bs[3][BN * 32];
  const int t = threadIdx.x;
  const int l = t & 63;
  const int w = t >> 6;
  const int wr = w >> 1, wc = w & 1;
  const int lrow = l & 15;
  const int lks = (((l >> 4) ^ ((lrow >> 1) & 3)) & 3) * 8;
  const int wg = (blockIdx.x & 7) * (gridDim.x >> 3) + (blockIdx.x >> 3);
  const int gyt = M >> 7;
  const int xt = wg / gyt;
  const int yt = wg - xt * gyt;
  const int m0 = yt * 128;
  const int n0 = xt * BN;
  const int arow = t >> 2;
  const int ach = (((t & 3) ^ ((t >> 3) & 3)) & 3) * 8;

  const bf16* pa0 = &A[(size_t)(m0 + arow) * K + ach];
  const bf16* pa1 = &A[(size_t)(m0 + arow + 64) * K + ach];
  const bf16* pb0 = &Bt[(size_t)(n0 + arow) * K + ach];
  auto STAGE = [&](int buf, int kt) {
    size_t off = (size_t)kt * 32;
    async_lds16(&As[buf][t * 8], pa0 + off);
    async_lds16(&As[buf][(256 + t) * 8], pa1 + off);
    async_lds16(&Bs[buf][t * 8], pb0 + off);
  };

  f32x4 acc[4][2] = {};
  const int nkt = K >> 5;
  STAGE(0, 0);
  STAGE(1, 1);
  int bcur = 0;
  for (int kt = 0; kt < nkt; ++kt) {
    if (kt + 1 < nkt) {
      asm volatile("s_waitcnt vmcnt(3)" ::: "memory");
    } else {
      asm volatile("s_waitcnt vmcnt(0)" ::: "memory");
    }
    __builtin_amdgcn_s_barrier();
    int bn2 = bcur + 2;
    if (bn2 >= 3) bn2 -= 3;
    if (kt + 2 < nkt) STAGE(bn2, kt + 2);

    short8 af[4], bfr[2];
#pragma unroll
    for (int i = 0; i < 4; ++i)
      af[i] = *(const short8*)&As[bcur][(wr * 64 + i * 16 + lrow) * 32 + lks];
#pragma unroll
    for (int j = 0; j < 2; ++j)
      bfr[j] = *(const short8*)&Bs[bcur][(wc * 32 + j * 16 + lrow) * 32 + lks];
    __builtin_amdgcn_s_setprio(1);
#pragma unroll
    for (int i = 0; i < 4; ++i)
#pragma unroll
      for (int j = 0; j < 2; ++j)
        acc[i][j] = __builtin_amdgcn_mfma_f32_16x16x32_bf16(af[i], bfr[j], acc[i][j], 0, 0, 0);
    __builtin_amdgcn_s_setprio(0);
    ++bcur;
    if (bcur == 3) bcur = 0;
  }

  const float qscale = 0.17002445f;  // (1/sqrt(72)) * log2(e)
#pragma unroll
  for (int i = 0; i < 4; ++i) {
    int rowb = m0 + wr * 64 + i * 16 + (l >> 4) * 4;
#pragma unroll
    for (int j = 0; j < 2; ++j) {
      int col = n0 + wc * 32 + j * 16 + lrow;
      float bv = bias[col];
      if (n0 < HID) {  // ---- q region: rope + scale ----
        int hh = col / HD, d = col - hh * HD;
        int pi = d >> 1;
        float sg = (d & 1) ? 1.f : -1.f;
        size_t qb = (size_t)hh * SEQ * HDP + d;
#pragma unroll
        for (int r2 = 0; r2 < 4; ++r2) {
          float vv = acc[i][j][r2] + bv;
          float pr = __shfl_xor(vv, 1, 64);
          int s = rowb + r2;
          float cs = cosb[s * 36 + pi], sn = sinb[s * 36 + pi];
          qp[qb + (size_t)s * HDP] = __float2bfloat16((vv * cs + pr * (sg * sn)) * qscale);
        }
      } else if (n0 < 2 * HID) {  // ---- k region: rope ----
        int c2 = col - HID;
        int hh = c2 / HD, d = c2 - hh * HD;
        int pi = d >> 1;
        float sg = (d & 1) ? 1.f : -1.f;
        size_t kb = (size_t)hh * SEQ * HDP + d;
#pragma unroll
        for (int r2 = 0; r2 < 4; ++r2) {
          float vv = acc[i][j][r2] + bv;
          float pr = __shfl_xor(vv, 1, 64);
          int s = rowb + r2;
          float cs = cosb[s * 36 + pi], sn = sinb[s * 36 + pi];
          kp[kb + (size_t)s * HDP] = __float2bfloat16(vv * cs + pr * (sg * sn));
        }
      } else {  // ---- v region: transpose write, 4 consecutive s packed ----
        int c2 = col - 2 * HID;
        int hh = c2 / HD, d = c2 - hh * HD;
        uint2 pk = make_uint2(cvt_pk2(acc[i][j][0] + bv, acc[i][j][1] + bv),
                              cvt_pk2(acc[i][j][2] + bv, acc[i][j][3] + bv));
        *(uint2*)&vt[((size_t)hh * HDP + d) * SEQ + rowb] = pk;
      }
    }
  }
}

// ---------------- flash attention (KVBLK=32, 4 waves, 40KB) ----------------
// Triple-buffered KV, QK(t+1)-ahead, swapped operands (lane-local softmax),
// exp2-domain, defer-max THR=8*log2(e)=11.54. l from the V ones-row (d=72).
// NO manual unroll (R16 lesson). Grid 768 = 3 blocks/CU.
// Must drain vmcnt(0) before exit (R13 race).
__global__ __launch_bounds__(256) void flash_attn(const bf16* __restrict__ q,
                                                  const bf16* __restrict__ kk,
                                                  const bf16* __restrict__ vT,
                                                  bf16* __restrict__ o) {
  __shared__ alignas(16) bf16 KV3[3 * 6144];
  __shared__ alignas(16) bf16 Pl[4][512];
  const int t = threadIdx.x;
  const int l = t & 63;
  const int w = t >> 6;
  const int g = l >> 4;
  const int lrow = l & 15;
  const int bid = blockIdx.x;
  const int kq = bid >> 3;
  const int h = (bid & 7) * 2 + (kq & 1);
  const int q0 = (kq >> 1) * 64 + w * 16;
  const int NT = SEQ / 32;

  const bf16* sbase[3];
  int smul[3];
#pragma unroll
  for (int i = 0; i < 3; ++i) {
    int s = t + i * 256;
    if (s < 384) {
      int cb = s >> 5, kv = s & 31;
      sbase[i] = kk + ((size_t)h * SEQ + kv) * HDP + cb * 8;
      smul[i] = 32 * HDP;
    } else {
      int vs = s - 384;
      int cb = vs / 96, d = vs - cb * 96;
      sbase[i] = vT + ((size_t)h * HDP + d) * SEQ + cb * 8;
      smul[i] = 32;
    }
  }
  auto STAGE = [&](int tile, int bufOff) {
#pragma unroll
    for (int i = 0; i < 3; ++i)
      async_lds16(&KV3[bufOff + (t + i * 256) * 8], sbase[i] + (size_t)tile * smul[i]);
  };

  short8 qf[3];
#pragma unroll
  for (int f = 0; f < 3; ++f)
    qf[f] = *(const short8*)&q[((size_t)h * SEQ + q0 + lrow) * HDP + f * 32 + g * 8];

  float m_r = -1e30f;
  f32x4 oa[5] = {};

  STAGE(0, 0);
  STAGE(1, 6144);
  STAGE(2, 12288);
  asm volatile("s_waitcnt vmcnt(6)" ::: "memory");
  __builtin_amdgcn_s_barrier();

  f32x4 stA[2] = {}, stB[2];
  int b0 = 0;
#pragma unroll
  for (int nf = 0; nf < 2; ++nf)
#pragma unroll
    for (int f = 0; f < 3; ++f) {
      short8 kfrag = *(const short8*)&KV3[0 + (f * 4 + g) * 256 + (nf * 16 + lrow) * 8];
      stA[nf] = __builtin_amdgcn_mfma_f32_16x16x32_bf16(kfrag, qf[f], stA[nf], 0, 0, 0);
    }

  for (int kt = 0; kt < NT - 1; ++kt) {
    int b1 = b0 + 6144;
    if (b1 == 18432) b1 = 0;
    asm volatile("s_waitcnt vmcnt(3)" ::: "memory");
    __builtin_amdgcn_s_barrier();

    stB[0] = (f32x4){0.f, 0.f, 0.f, 0.f};
    stB[1] = (f32x4){0.f, 0.f, 0.f, 0.f};
    __builtin_amdgcn_s_setprio(1);
#pragma unroll
    for (int nf = 0; nf < 2; ++nf)
#pragma unroll
      for (int f = 0; f < 3; ++f) {
        short8 kfrag = *(const short8*)&KV3[b1 + (f * 4 + g) * 256 + (nf * 16 + lrow) * 8];
        stB[nf] = __builtin_amdgcn_mfma_f32_16x16x32_bf16(kfrag, qf[f], stB[nf], 0, 0, 0);
      }
    __builtin_amdgcn_s_setprio(0);

    float pmax = fmaxf(fmaxf(fmaxf(stA[0][0], stA[0][1]), fmaxf(stA[0][2], stA[0][3])),
                       fmaxf(fmaxf(stA[1][0], stA[1][1]), fmaxf(stA[1][2], stA[1][3])));
    if (!__all(pmax - m_r <= 11.54f)) {
      float rm = pmax;
      rm = fmaxf(rm, __shfl_xor(rm, 16, 64));
      rm = fmaxf(rm, __shfl_xor(rm, 32, 64));
      float mn = fmaxf(m_r, rm);
      float alpha = exp2a(m_r - mn);
#pragma unroll
      for (int nf = 0; nf < 5; ++nf)
#pragma unroll
        for (int r = 0; r < 4; ++r) oa[nf][r] *= alpha;
      m_r = mn;
    }
#pragma unroll
    for (int nf = 0; nf < 2; ++nf)
#pragma unroll
      for (int r = 0; r < 4; ++r) stA[nf][r] = exp2a(stA[nf][r] - m_r);

#pragma unroll
    for (int nf = 0; nf < 2; ++nf) {
      uint2* dst = (uint2*)&Pl[w][(2 * nf + (g >> 1)) * 128 + lrow * 8 + (g & 1) * 4];
      *dst = make_uint2(cvt_pk2(stA[nf][0], stA[nf][1]), cvt_pk2(stA[nf][2], stA[nf][3]));
    }

    {
      short8 pa = *(const short8*)&Pl[w][g * 128 + lrow * 8];
      __builtin_amdgcn_s_setprio(1);
#pragma unroll
      for (int nf = 0; nf < 5; ++nf) {
        short8 bv = *(const short8*)&KV3[b0 + 3072 + g * 768 + (nf * 16 + lrow) * 8];
        oa[nf] = __builtin_amdgcn_mfma_f32_16x16x32_bf16(bv, pa, oa[nf], 0, 0, 0);
      }
      __builtin_amdgcn_s_setprio(0);
    }

    asm volatile("s_waitcnt lgkmcnt(0)" ::: "memory");
    __builtin_amdgcn_s_barrier();
    int s = kt + 3;
    if (s >= NT) s -= NT;
    STAGE(s, b0);
    stA[0] = stB[0];
    stA[1] = stB[1];
    b0 = b1;
  }

  // epilogue tile NT-1
  {
    float pmax = fmaxf(fmaxf(fmaxf(stA[0][0], stA[0][1]), fmaxf(stA[0][2], stA[0][3])),
                       fmaxf(fmaxf(stA[1][0], stA[1][1]), fmaxf(stA[1][2], stA[1][3])));
    if (!__all(pmax - m_r <= 11.54f)) {
      float rm = pmax;
      rm = fmaxf(rm, __shfl_xor(rm, 16, 64));
      rm = fmaxf(rm, __shfl_xor(rm, 32, 64));
      float mn = fmaxf(m_r, rm);
      float alpha = exp2a(m_r - mn);
#pragma unroll
      for (int nf = 0; nf < 5; ++nf)
#pragma unroll
        for (int r = 0; r < 4; ++r) oa[nf][r] *= alpha;
      m_r = mn;
    }
#pragma unroll
    for (int nf = 0; nf < 2; ++nf)
#pragma unroll
      for (int r = 0; r < 4; ++r) stA[nf][r] = exp2a(stA[nf][r] - m_r);
#pragma unroll
    for (int nf = 0; nf < 2; ++nf) {
      uint2* dst = (uint2*)&Pl[w][(2 * nf + (g >> 1)) * 128 + lrow * 8 + (g & 1) * 4];
      *dst = make_uint2(cvt_pk2(stA[nf][0], stA[nf][1]), cvt_pk2(stA[nf][2], stA[nf][3]));
    }
    short8 pa = *(const short8*)&Pl[w][g * 128 + lrow * 8];
#pragma unroll
    for (int nf = 0; nf < 5; ++nf) {
      short8 bv = *(const short8*)&KV3[b0 + 3072 + g * 768 + (nf * 16 + lrow) * 8];
      oa[nf] = __builtin_amdgcn_mfma_f32_16x16x32_bf16(bv, pa, oa[nf], 0, 0, 0);
    }
  }

  asm volatile("s_waitcnt vmcnt(0)" ::: "memory");

  float lt = __shfl(oa[4][0], 32 + lrow, 64);
  float rcp = 1.f / lt;
  size_t obase = (size_t)(q0 + lrow) * HID + h * HD;
#pragma unroll
  for (int nf = 0; nf < 5; ++nf) {
    int d = nf * 16 + g * 4;
    if (d + 3 < HD) {
      uint2 pk = make_uint2(cvt_pk2(oa[nf][0] * rcp, oa[nf][1] * rcp),
                            cvt_pk2(oa[nf][2] * rcp, oa[nf][3] * rcp));
      *(uint2*)&o[obase + d] = pk;
    }
  }
}

// ---------------- launch ----------------
extern "C" void kernel_launch(void* const* d_in, const int* in_sizes, int n_in,
                              void* d_out, int out_size, void* d_ws, size_t ws_size,
                              hipStream_t stream) {
  (void)in_sizes; (void)n_in; (void)out_size;
  const float* hidden = (const float*)d_in[0];
  const float* cosb = (const float*)d_in[1];
  const float* sinb = (const float*)d_in[2];
  const float* ln0g = (const float*)d_in[3];
  const float* ln0b = (const float*)d_in[4];
  const float* ln1g = (const float*)d_in[5];
  const float* ln1b = (const float*)d_in[6];
  const float* wqkv = (const float*)d_in[7];
  const float* bqkv = (const float*)d_in[8];
  const float* wo = (const float*)d_in[9];
  const float* bo = (const float*)d_in[10];
  const float* w0 = (const float*)d_in[11];
  const float* b0 = (const float*)d_in[12];
  const float* w1 = (const float*)d_in[13];
  const float* b1 = (const float*)d_in[14];

  char* p = (char*)d_ws;
  auto alloc = [&](size_t n) {
    char* r = p;
    p += (n + 255) & ~(size_t)255;
    return r;
  };
  bf16* wqkv_bf = (bf16*)alloc((size_t)3 * HID * HID * 2);
  bf16* wo_bf = (bf16*)alloc((size_t)HID * HID * 2);
  bf16* fc0_bf = (bf16*)alloc((size_t)MLPP * HID * 2);
  bf16* fc1_bf = (bf16*)alloc((size_t)HID * MLPP * 2);
  bf16* ln0_bf = (bf16*)alloc((size_t)SEQ * HID * 2);
  bf16* qp = (bf16*)alloc((size_t)NHEAD * SEQ * HDP * 2);
  bf16* kp = (bf16*)alloc((size_t)NHEAD * SEQ * HDP * 2);
  bf16* vt = (bf16*)alloc((size_t)NHEAD * HDP * SEQ * 2);
  bf16* attn_bf = (bf16*)alloc((size_t)SEQ * HID * 2);
  bf16* h1b = (bf16*)alloc((size_t)SEQ * HID * 2);
  bf16* ln1_bf = (bf16*)alloc((size_t)SEQ * HID * 2);
  bf16* gelu_bf = (bf16*)alloc((size_t)SEQ * MLPP * 2);
  if ((size_t)(p - (char*)d_ws) > ws_size) return;

  dim3 blk(256);
  prep_k<<<SEQ + 1024, blk, 0, stream>>>(hidden, ln0g, ln0b, wqkv, wo, w0, w1, ln0_bf,
                                         (unsigned*)wqkv_bf, (unsigned*)wo_bf,
                                         (unsigned*)fc0_bf, (unsigned*)fc1_bf, qp, kp, vt);
  gemm_qkv<<<dim3((3 * HID / 64) * (SEQ / 128)), blk, 0, stream>>>(
      ln0_bf, wqkv_bf, bqkv, cosb, sinb, qp, kp, vt);
  flash_attn<<<dim3(768), blk, 0, stream>>>(qp, kp, vt, attn_bf);
  gemm_bf16<1, 64><<<dim3((HID / 64) * (SEQ / 128)), blk, 0, stream>>>(
      attn_bf, wo_bf, bo, HID, hidden, nullptr, nullptr, h1b, SEQ, HID, HID);
  ln_bf_k<<<SEQ, blk, 0, stream>>>(h1b, ln1g, ln1b, ln1_bf);
  gemm_bf16<2, 64><<<dim3((MLPP / 64) * (SEQ / 128)), blk, 0, stream>>>(
      ln1_bf, fc0_bf, b0, MLPD, nullptr, nullptr, nullptr, gelu_bf, SEQ, MLPP, HID);
  gemm_bf16<3, 64><<<dim3((HID / 64) * (SEQ / 128)), blk, 0, stream>>>(
      gelu_bf, fc1_bf, b1, HID, nullptr, h1b, (float*)d_out, nullptr, SEQ, HID, MLPP);
}

// Round 22
// 325.688 us; speedup vs baseline: 1.0597x; 1.0597x over previous
//
#include <hip/hip_runtime.h>
#include <hip/hip_bf16.h>
#include <math.h>

typedef __hip_bfloat16 bf16;
typedef __attribute__((ext_vector_type(8))) short short8;
typedef __attribute__((ext_vector_type(4))) short short4v;
typedef __attribute__((ext_vector_type(4))) float f32x4;

#define SEQ 3072
#define HID 1152
#define NHEAD 16
#define HD 72
#define HDP 96
#define MLPD 4304
#define MLPP 4352

__device__ __forceinline__ void async_lds16(void* lds, const void* g) {
  __builtin_amdgcn_global_load_lds((const __attribute__((address_space(1))) void*)g,
                                   (__attribute__((address_space(3))) void*)lds,
                                   16, 0, 0);
}

// one v_cvt_pk_bf16_f32: a -> low16, b -> high16 (RNE)
__device__ __forceinline__ unsigned cvt_pk2(float a, float b) {
  unsigned r;
  asm("v_cvt_pk_bf16_f32 %0, %1, %2" : "=v"(r) : "v"(a), "v"(b));
  return r;
}

// raw v_exp_f32: 2^x
__device__ __forceinline__ float exp2a(float x) {
  float r;
  asm("v_exp_f32 %0, %1" : "=v"(r) : "v"(x));
  return r;
}

// bf16 pair (packed in u32) -> two floats, bit-ops only
__device__ __forceinline__ float bflo(unsigned u) { return __uint_as_float(u << 16); }
__device__ __forceinline__ float bfhi(unsigned u) { return __uint_as_float(u & 0xffff0000u); }

// ---------------- prep: LN0 (blocks < SEQ) + weight casts + q/k/v pads (rest) ----------------
__global__ __launch_bounds__(256) void prep_k(const float* __restrict__ hidden,
                                              const float* __restrict__ ln0g,
                                              const float* __restrict__ ln0b,
                                              const float* __restrict__ wqkv,
                                              const float* __restrict__ wo,
                                              const float* __restrict__ w0,
                                              const float* __restrict__ w1,
                                              bf16* __restrict__ ln0_o,
                                              unsigned* __restrict__ wqkv_o,
                                              unsigned* __restrict__ wo_o,
                                              unsigned* __restrict__ fc0_o,
                                              unsigned* __restrict__ fc1_o,
                                              bf16* __restrict__ qp,
                                              bf16* __restrict__ kp,
                                              bf16* __restrict__ vt) {
  if (blockIdx.x < SEQ) {
    // ---- LN0 row ----
    int row = blockIdx.x;
    const float4* xr = (const float4*)(hidden + (size_t)row * HID);
    float sum = 0.f, sq = 0.f;
    for (int c = threadIdx.x; c < HID / 4; c += 256) {
      float4 u = xr[c];
      sum += u.x + u.y + u.z + u.w;
      sq += u.x * u.x + u.y * u.y + u.z * u.z + u.w * u.w;
    }
#pragma unroll
    for (int off = 32; off > 0; off >>= 1) {
      sum += __shfl_down(sum, off, 64);
      sq += __shfl_down(sq, off, 64);
    }
    __shared__ float red[8];
    int wv = threadIdx.x >> 6;
    if ((threadIdx.x & 63) == 0) { red[wv] = sum; red[4 + wv] = sq; }
    __syncthreads();
    if (threadIdx.x == 0) {
      red[0] = red[0] + red[1] + red[2] + red[3];
      red[4] = red[4] + red[5] + red[6] + red[7];
    }
    __syncthreads();
    float mu = red[0] * (1.f / HID);
    float var = red[4] * (1.f / HID) - mu * mu;
    float inv = rsqrtf(var + 1e-5f);
    uint2* o4 = (uint2*)(ln0_o + (size_t)row * HID);
    const float4* g4 = (const float4*)ln0g;
    const float4* b4 = (const float4*)ln0b;
    for (int c = threadIdx.x; c < HID / 4; c += 256) {
      float4 u = xr[c], gg = g4[c], bb = b4[c];
      o4[c] = make_uint2(cvt_pk2((u.x - mu) * inv * gg.x + bb.x, (u.y - mu) * inv * gg.y + bb.y),
                         cvt_pk2((u.z - mu) * inv * gg.z + bb.z, (u.w - mu) * inv * gg.w + bb.w));
    }
    return;
  }
  // ---- weight casts + pads (grid-stride over the remaining blocks) ----
  const int n0 = 3 * HID * HID / 4;
  const int n1 = HID * HID / 4;
  const int n2 = MLPP * HID / 4;
  const int n3 = HID * MLPP / 4;
  const int n4 = NHEAD * SEQ * 6;   // qp pads: d 72..95 = 6 uint2 per (h,s)
  const int n5 = n4;                // kp pads
  const int n6 = NHEAD * 24 * 768;  // vt rows d=72..95: 768 uint2 per (h,d)
  const int total = n0 + n1 + n2 + n3 + n4 + n5 + n6;
  int nb = gridDim.x - SEQ;
  int stride = nb * blockDim.x;
  for (int i = (blockIdx.x - SEQ) * blockDim.x + threadIdx.x; i < total; i += stride) {
    if (i < n0) {
      float4 u = ((const float4*)wqkv)[i];
      ((uint2*)wqkv_o)[i] = make_uint2(cvt_pk2(u.x, u.y), cvt_pk2(u.z, u.w));
    } else if (i < n0 + n1) {
      int k = i - n0;
      float4 u = ((const float4*)wo)[k];
      ((uint2*)wo_o)[k] = make_uint2(cvt_pk2(u.x, u.y), cvt_pk2(u.z, u.w));
    } else if (i < n0 + n1 + n2) {
      int k = i - n0 - n1;
      int r = k / (HID / 4);
      uint2 w = make_uint2(0u, 0u);
      if (r < MLPD) {
        float4 u = ((const float4*)w0)[k];
        w = make_uint2(cvt_pk2(u.x, u.y), cvt_pk2(u.z, u.w));
      }
      ((uint2*)fc0_o)[k] = w;
    } else if (i < n0 + n1 + n2 + n3) {
      int k = i - n0 - n1 - n2;
      int r = k / (MLPP / 4), c4 = k - r * (MLPP / 4);
      uint2 w = make_uint2(0u, 0u);
      if (c4 < MLPD / 4) {
        float4 u = ((const float4*)w1)[r * (MLPD / 4) + c4];
        w = make_uint2(cvt_pk2(u.x, u.y), cvt_pk2(u.z, u.w));
      }
      ((uint2*)fc1_o)[k] = w;
    } else if (i < n0 + n1 + n2 + n3 + n4) {
      int k = i - (n0 + n1 + n2 + n3);
      int hs = k / 6, u = k - hs * 6;
      ((uint2*)(qp + (size_t)hs * HDP + 72))[u] = make_uint2(0u, 0u);
    } else if (i < n0 + n1 + n2 + n3 + n4 + n5) {
      int k = i - (n0 + n1 + n2 + n3 + n4);
      int hs = k / 6, u = k - hs * 6;
      ((uint2*)(kp + (size_t)hs * HDP + 72))[u] = make_uint2(0u, 0u);
    } else {
      int k = i - (n0 + n1 + n2 + n3 + n4 + n5);
      int hd = k / 768, s4 = k - hd * 768;
      int d = 72 + (hd % 24);
      int hh = hd / 24;
      unsigned val = (d == 72) ? 0x3F803F80u : 0u;  // bf16 1.0 pair (ones-row for l)
      ((uint2*)(vt + ((size_t)hh * HDP + d) * SEQ))[s4] = make_uint2(val, val);
    }
  }
}

// ---------------- layernorm (bf16 in -> bf16 out) ----------------
__global__ __launch_bounds__(256) void ln_bf_k(const bf16* __restrict__ x,
                                               const float* __restrict__ g,
                                               const float* __restrict__ b,
                                               bf16* __restrict__ o) {
  int row = blockIdx.x;
  const uint2* xr = (const uint2*)(x + (size_t)row * HID);
  float sum = 0.f, sq = 0.f;
  for (int c = threadIdx.x; c < HID / 4; c += 256) {
    uint2 u = xr[c];
    float a0 = bflo(u.x), a1 = bfhi(u.x), a2 = bflo(u.y), a3 = bfhi(u.y);
    sum += (a0 + a1) + (a2 + a3);
    sq += (a0 * a0 + a1 * a1) + (a2 * a2 + a3 * a3);
  }
#pragma unroll
  for (int off = 32; off > 0; off >>= 1) {
    sum += __shfl_down(sum, off, 64);
    sq += __shfl_down(sq, off, 64);
  }
  __shared__ float red[8];
  int wv = threadIdx.x >> 6;
  if ((threadIdx.x & 63) == 0) { red[wv] = sum; red[4 + wv] = sq; }
  __syncthreads();
  if (threadIdx.x == 0) {
    red[0] = red[0] + red[1] + red[2] + red[3];
    red[4] = red[4] + red[5] + red[6] + red[7];
  }
  __syncthreads();
  float mu = red[0] * (1.f / HID);
  float var = red[4] * (1.f / HID) - mu * mu;
  float inv = rsqrtf(var + 1e-5f);
  uint2* o4 = (uint2*)(o + (size_t)row * HID);
  const float4* g4 = (const float4*)g;
  const float4* b4 = (const float4*)b;
  for (int c = threadIdx.x; c < HID / 4; c += 256) {
    uint2 u = xr[c];
    float4 gg = g4[c], bb = b4[c];
    float a0 = bflo(u.x), a1 = bfhi(u.x), a2 = bflo(u.y), a3 = bfhi(u.y);
    o4[c] = make_uint2(cvt_pk2((a0 - mu) * inv * gg.x + bb.x, (a1 - mu) * inv * gg.y + bb.y),
                       cvt_pk2((a2 - mu) * inv * gg.z + bb.z, (a3 - mu) * inv * gg.w + bb.w));
  }
}

// ---------------- GEMM: C[M][N] = A[M][K] @ Bt[N][K]^T  (+ epilogue) ----------------
// 3 LDS buffers, depth-2 prefetch, counted vmcnt, bijective XCD swizzle,
// LDS chunk XOR-swizzle. BN=64: 36KB LDS -> 4 blocks/CU (residency lever;
// wins on small-N WO/FC1/FC0, LOSES on wide-N QKV — R21: A-panel re-reads
// double and beat the occupancy gain).
// EPI 1: +bias+resf -> bf16 (WO+hidden)   2: +bias,gelu -> bf16   3: +bias+resb -> fp32
template <int EPI, int BN>
__global__ __launch_bounds__(256) void gemm_bf16(const bf16* __restrict__ A,
                                                 const bf16* __restrict__ Bt,
                                                 const float* __restrict__ bias, int nbias,
                                                 const float* __restrict__ resf,
                                                 const bf16* __restrict__ resb,
                                                 float* __restrict__ outf,
                                                 bf16* __restrict__ outb,
                                                 int M, int N, int K) {
  constexpr int NFR = (BN == 128) ? 4 : 2;
  __shared__ bf16 As[3][128 * 32];
  __shared__ bf16 Bs[3][BN * 32];
  const int t = threadIdx.x;
  const int l = t & 63;
  const int w = t >> 6;
  const int wr = w >> 1, wc = w & 1;
  const int lrow = l & 15;
  const int lks = (((l >> 4) ^ ((lrow >> 1) & 3)) & 3) * 8;
  const int wg = (blockIdx.x & 7) * (gridDim.x >> 3) + (blockIdx.x >> 3);
  const int gyt = M >> 7;
  const int xt = wg / gyt;
  const int yt = wg - xt * gyt;
  const int m0 = yt * 128;
  const int n0 = xt * BN;
  const int arow = t >> 2;
  const int ach = (((t & 3) ^ ((t >> 3) & 3)) & 3) * 8;

  const bf16* pa0 = &A[(size_t)(m0 + arow) * K + ach];
  const bf16* pa1 = &A[(size_t)(m0 + arow + 64) * K + ach];
  const bf16* pb0 = &Bt[(size_t)(n0 + arow) * K + ach];
  const bf16* pb1 = (BN == 128) ? &Bt[(size_t)(n0 + arow + 64) * K + ach] : pb0;
  auto STAGE = [&](int buf, int kt) {
    size_t off = (size_t)kt * 32;
    async_lds16(&As[buf][t * 8], pa0 + off);
    async_lds16(&As[buf][(256 + t) * 8], pa1 + off);
    async_lds16(&Bs[buf][t * 8], pb0 + off);
    if constexpr (BN == 128) async_lds16(&Bs[buf][(256 + t) * 8], pb1 + off);
  };

  f32x4 acc[4][NFR] = {};
  const int nkt = K >> 5;
  STAGE(0, 0);
  STAGE(1, 1);
  int bcur = 0;
  for (int kt = 0; kt < nkt; ++kt) {
    if (kt + 1 < nkt) {
      if constexpr (BN == 128)
        asm volatile("s_waitcnt vmcnt(4)" ::: "memory");
      else
        asm volatile("s_waitcnt vmcnt(3)" ::: "memory");
    } else {
      asm volatile("s_waitcnt vmcnt(0)" ::: "memory");
    }
    __builtin_amdgcn_s_barrier();
    int bn2 = bcur + 2;
    if (bn2 >= 3) bn2 -= 3;
    if (kt + 2 < nkt) STAGE(bn2, kt + 2);

    short8 af[4], bfr[NFR];
#pragma unroll
    for (int i = 0; i < 4; ++i)
      af[i] = *(const short8*)&As[bcur][(wr * 64 + i * 16 + lrow) * 32 + lks];
#pragma unroll
    for (int j = 0; j < NFR; ++j)
      bfr[j] = *(const short8*)&Bs[bcur][(wc * (BN >> 1) + j * 16 + lrow) * 32 + lks];
    __builtin_amdgcn_s_setprio(1);
#pragma unroll
    for (int i = 0; i < 4; ++i)
#pragma unroll
      for (int j = 0; j < NFR; ++j)
        acc[i][j] = __builtin_amdgcn_mfma_f32_16x16x32_bf16(af[i], bfr[j], acc[i][j], 0, 0, 0);
    __builtin_amdgcn_s_setprio(0);
    ++bcur;
    if (bcur == 3) bcur = 0;
  }

#pragma unroll
  for (int i = 0; i < 4; ++i) {
    int rowb = m0 + wr * 64 + i * 16 + (l >> 4) * 4;
#pragma unroll
    for (int j = 0; j < NFR; ++j) {
      int col = n0 + wc * (BN >> 1) + j * 16 + lrow;
      float bv = (col < nbias) ? bias[col] : 0.f;
#pragma unroll
      for (int r2 = 0; r2 < 4; ++r2) {
        size_t idx = (size_t)(rowb + r2) * N + col;
        float v = acc[i][j][r2] + bv;
        if (EPI == 1) {
          outb[idx] = __float2bfloat16(v + resf[idx]);
        } else if (EPI == 2) {
          float u = 0.7978845608028654f * (v + 0.044715f * v * v * v);
          u = fminf(fmaxf(u, -15.f), 15.f);
          float tt = __expf(2.f * u);
          outb[idx] = __float2bfloat16(v * tt / (tt + 1.f));
        } else {
          outf[idx] = v + __bfloat162float(resb[idx]);
        }
      }
    }
  }
}

// ---------------- QKV GEMM with fused rope/split epilogue (BN=128) ----------------
// BN=128 is optimal here (R21: BN=64 regressed +19us — wide N=3456 doubles
// A-panel re-reads). Epilogue applies rope to q/k (pair via shfl_xor(1): col
// parity == lane parity, pairs never cross the 16-lane group), scales q by
// (1/sqrt(72))*log2(e), and writes v TRANSPOSED (vt[h][d][s], packed 4-s
// uint2). Region boundaries (1152, 2304) are multiples of 128 so no tile
// straddles regions.
__global__ __launch_bounds__(256) void gemm_qkv(const bf16* __restrict__ A,
                                                const bf16* __restrict__ Bt,
                                                const float* __restrict__ bias,
                                                const float* __restrict__ cosb,
                                                const float* __restrict__ sinb,
                                                bf16* __restrict__ qp,
                                                bf16* __restrict__ kp,
                                                bf16* __restrict__ vt) {
  constexpr int BN = 128;
  const int M = SEQ, K = HID;
  __shared__ bf16 As[3][128 * 32];
  __shared__ bf16 Bs[3][BN * 32];
  const int t = threadIdx.x;
  const int l = t & 63;
  const int w = t >> 6;
  const int wr = w >> 1, wc = w & 1;
  const int lrow = l & 15;
  const int lks = (((l >> 4) ^ ((lrow >> 1) & 3)) & 3) * 8;
  const int wg = (blockIdx.x & 7) * (gridDim.x >> 3) + (blockIdx.x >> 3);
  const int gyt = M >> 7;
  const int xt = wg / gyt;
  const int yt = wg - xt * gyt;
  const int m0 = yt * 128;
  const int n0 = xt * BN;
  const int arow = t >> 2;
  const int ach = (((t & 3) ^ ((t >> 3) & 3)) & 3) * 8;

  const bf16* pa0 = &A[(size_t)(m0 + arow) * K + ach];
  const bf16* pa1 = &A[(size_t)(m0 + arow + 64) * K + ach];
  const bf16* pb0 = &Bt[(size_t)(n0 + arow) * K + ach];
  const bf16* pb1 = &Bt[(size_t)(n0 + arow + 64) * K + ach];
  auto STAGE = [&](int buf, int kt) {
    size_t off = (size_t)kt * 32;
    async_lds16(&As[buf][t * 8], pa0 + off);
    async_lds16(&As[buf][(256 + t) * 8], pa1 + off);
    async_lds16(&Bs[buf][t * 8], pb0 + off);
    async_lds16(&Bs[buf][(256 + t) * 8], pb1 + off);
  };

  f32x4 acc[4][4] = {};
  const int nkt = K >> 5;
  STAGE(0, 0);
  STAGE(1, 1);
  int bcur = 0;
  for (int kt = 0; kt < nkt; ++kt) {
    if (kt + 1 < nkt) {
      asm volatile("s_waitcnt vmcnt(4)" ::: "memory");
    } else {
      asm volatile("s_waitcnt vmcnt(0)" ::: "memory");
    }
    __builtin_amdgcn_s_barrier();
    int bn2 = bcur + 2;
    if (bn2 >= 3) bn2 -= 3;
    if (kt + 2 < nkt) STAGE(bn2, kt + 2);

    short8 af[4], bfr[4];
#pragma unroll
    for (int i = 0; i < 4; ++i)
      af[i] = *(const short8*)&As[bcur][(wr * 64 + i * 16 + lrow) * 32 + lks];
#pragma unroll
    for (int j = 0; j < 4; ++j)
      bfr[j] = *(const short8*)&Bs[bcur][(wc * 64 + j * 16 + lrow) * 32 + lks];
    __builtin_amdgcn_s_setprio(1);
#pragma unroll
    for (int i = 0; i < 4; ++i)
#pragma unroll
      for (int j = 0; j < 4; ++j)
        acc[i][j] = __builtin_amdgcn_mfma_f32_16x16x32_bf16(af[i], bfr[j], acc[i][j], 0, 0, 0);
    __builtin_amdgcn_s_setprio(0);
    ++bcur;
    if (bcur == 3) bcur = 0;
  }

  const float qscale = 0.17002445f;  // (1/sqrt(72)) * log2(e)
#pragma unroll
  for (int i = 0; i < 4; ++i) {
    int rowb = m0 + wr * 64 + i * 16 + (l >> 4) * 4;
#pragma unroll
    for (int j = 0; j < 4; ++j) {
      int col = n0 + wc * 64 + j * 16 + lrow;
      float bv = bias[col];
      if (n0 < HID) {  // ---- q region: rope + scale ----
        int hh = col / HD, d = col - hh * HD;
        int pi = d >> 1;
        float sg = (d & 1) ? 1.f : -1.f;
        size_t qb = (size_t)hh * SEQ * HDP + d;
#pragma unroll
        for (int r2 = 0; r2 < 4; ++r2) {
          float vv = acc[i][j][r2] + bv;
          float pr = __shfl_xor(vv, 1, 64);
          int s = rowb + r2;
          float cs = cosb[s * 36 + pi], sn = sinb[s * 36 + pi];
          qp[qb + (size_t)s * HDP] = __float2bfloat16((vv * cs + pr * (sg * sn)) * qscale);
        }
      } else if (n0 < 2 * HID) {  // ---- k region: rope ----
        int c2 = col - HID;
        int hh = c2 / HD, d = c2 - hh * HD;
        int pi = d >> 1;
        float sg = (d & 1) ? 1.f : -1.f;
        size_t kb = (size_t)hh * SEQ * HDP + d;
#pragma unroll
        for (int r2 = 0; r2 < 4; ++r2) {
          float vv = acc[i][j][r2] + bv;
          float pr = __shfl_xor(vv, 1, 64);
          int s = rowb + r2;
          float cs = cosb[s * 36 + pi], sn = sinb[s * 36 + pi];
          kp[kb + (size_t)s * HDP] = __float2bfloat16(vv * cs + pr * (sg * sn));
        }
      } else {  // ---- v region: transpose write, 4 consecutive s packed ----
        int c2 = col - 2 * HID;
        int hh = c2 / HD, d = c2 - hh * HD;
        uint2 pk = make_uint2(cvt_pk2(acc[i][j][0] + bv, acc[i][j][1] + bv),
                              cvt_pk2(acc[i][j][2] + bv, acc[i][j][3] + bv));
        *(uint2*)&vt[((size_t)hh * HDP + d) * SEQ + rowb] = pk;
      }
    }
  }
}

// ---------------- flash attention (KVBLK=32, 4 waves, 40KB) ----------------
// Triple-buffered KV, QK(t+1)-ahead, swapped operands (lane-local softmax),
// exp2-domain, defer-max THR=8*log2(e)=11.54. l from the V ones-row (d=72).
// NO manual unroll (R16 lesson). Grid 768 = 3 blocks/CU.
// Must drain vmcnt(0) before exit (R13 race).
__global__ __launch_bounds__(256) void flash_attn(const bf16* __restrict__ q,
                                                  const bf16* __restrict__ kk,
                                                  const bf16* __restrict__ vT,
                                                  bf16* __restrict__ o) {
  __shared__ alignas(16) bf16 KV3[3 * 6144];
  __shared__ alignas(16) bf16 Pl[4][512];
  const int t = threadIdx.x;
  const int l = t & 63;
  const int w = t >> 6;
  const int g = l >> 4;
  const int lrow = l & 15;
  const int bid = blockIdx.x;
  const int kq = bid >> 3;
  const int h = (bid & 7) * 2 + (kq & 1);
  const int q0 = (kq >> 1) * 64 + w * 16;
  const int NT = SEQ / 32;

  const bf16* sbase[3];
  int smul[3];
#pragma unroll
  for (int i = 0; i < 3; ++i) {
    int s = t + i * 256;
    if (s < 384) {
      int cb = s >> 5, kv = s & 31;
      sbase[i] = kk + ((size_t)h * SEQ + kv) * HDP + cb * 8;
      smul[i] = 32 * HDP;
    } else {
      int vs = s - 384;
      int cb = vs / 96, d = vs - cb * 96;
      sbase[i] = vT + ((size_t)h * HDP + d) * SEQ + cb * 8;
      smul[i] = 32;
    }
  }
  auto STAGE = [&](int tile, int bufOff) {
#pragma unroll
    for (int i = 0; i < 3; ++i)
      async_lds16(&KV3[bufOff + (t + i * 256) * 8], sbase[i] + (size_t)tile * smul[i]);
  };

  short8 qf[3];
#pragma unroll
  for (int f = 0; f < 3; ++f)
    qf[f] = *(const short8*)&q[((size_t)h * SEQ + q0 + lrow) * HDP + f * 32 + g * 8];

  float m_r = -1e30f;
  f32x4 oa[5] = {};

  STAGE(0, 0);
  STAGE(1, 6144);
  STAGE(2, 12288);
  asm volatile("s_waitcnt vmcnt(6)" ::: "memory");
  __builtin_amdgcn_s_barrier();

  f32x4 stA[2] = {}, stB[2];
  int b0 = 0;
#pragma unroll
  for (int nf = 0; nf < 2; ++nf)
#pragma unroll
    for (int f = 0; f < 3; ++f) {
      short8 kfrag = *(const short8*)&KV3[0 + (f * 4 + g) * 256 + (nf * 16 + lrow) * 8];
      stA[nf] = __builtin_amdgcn_mfma_f32_16x16x32_bf16(kfrag, qf[f], stA[nf], 0, 0, 0);
    }

  for (int kt = 0; kt < NT - 1; ++kt) {
    int b1 = b0 + 6144;
    if (b1 == 18432) b1 = 0;
    asm volatile("s_waitcnt vmcnt(3)" ::: "memory");
    __builtin_amdgcn_s_barrier();

    stB[0] = (f32x4){0.f, 0.f, 0.f, 0.f};
    stB[1] = (f32x4){0.f, 0.f, 0.f, 0.f};
    __builtin_amdgcn_s_setprio(1);
#pragma unroll
    for (int nf = 0; nf < 2; ++nf)
#pragma unroll
      for (int f = 0; f < 3; ++f) {
        short8 kfrag = *(const short8*)&KV3[b1 + (f * 4 + g) * 256 + (nf * 16 + lrow) * 8];
        stB[nf] = __builtin_amdgcn_mfma_f32_16x16x32_bf16(kfrag, qf[f], stB[nf], 0, 0, 0);
      }
    __builtin_amdgcn_s_setprio(0);

    float pmax = fmaxf(fmaxf(fmaxf(stA[0][0], stA[0][1]), fmaxf(stA[0][2], stA[0][3])),
                       fmaxf(fmaxf(stA[1][0], stA[1][1]), fmaxf(stA[1][2], stA[1][3])));
    if (!__all(pmax - m_r <= 11.54f)) {
      float rm = pmax;
      rm = fmaxf(rm, __shfl_xor(rm, 16, 64));
      rm = fmaxf(rm, __shfl_xor(rm, 32, 64));
      float mn = fmaxf(m_r, rm);
      float alpha = exp2a(m_r - mn);
#pragma unroll
      for (int nf = 0; nf < 5; ++nf)
#pragma unroll
        for (int r = 0; r < 4; ++r) oa[nf][r] *= alpha;
      m_r = mn;
    }
#pragma unroll
    for (int nf = 0; nf < 2; ++nf)
#pragma unroll
      for (int r = 0; r < 4; ++r) stA[nf][r] = exp2a(stA[nf][r] - m_r);

#pragma unroll
    for (int nf = 0; nf < 2; ++nf) {
      uint2* dst = (uint2*)&Pl[w][(2 * nf + (g >> 1)) * 128 + lrow * 8 + (g & 1) * 4];
      *dst = make_uint2(cvt_pk2(stA[nf][0], stA[nf][1]), cvt_pk2(stA[nf][2], stA[nf][3]));
    }

    {
      short8 pa = *(const short8*)&Pl[w][g * 128 + lrow * 8];
      __builtin_amdgcn_s_setprio(1);
#pragma unroll
      for (int nf = 0; nf < 5; ++nf) {
        short8 bv = *(const short8*)&KV3[b0 + 3072 + g * 768 + (nf * 16 + lrow) * 8];
        oa[nf] = __builtin_amdgcn_mfma_f32_16x16x32_bf16(bv, pa, oa[nf], 0, 0, 0);
      }
      __builtin_amdgcn_s_setprio(0);
    }

    asm volatile("s_waitcnt lgkmcnt(0)" ::: "memory");
    __builtin_amdgcn_s_barrier();
    int s = kt + 3;
    if (s >= NT) s -= NT;
    STAGE(s, b0);
    stA[0] = stB[0];
    stA[1] = stB[1];
    b0 = b1;
  }

  // epilogue tile NT-1
  {
    float pmax = fmaxf(fmaxf(fmaxf(stA[0][0], stA[0][1]), fmaxf(stA[0][2], stA[0][3])),
                       fmaxf(fmaxf(stA[1][0], stA[1][1]), fmaxf(stA[1][2], stA[1][3])));
    if (!__all(pmax - m_r <= 11.54f)) {
      float rm = pmax;
      rm = fmaxf(rm, __shfl_xor(rm, 16, 64));
      rm = fmaxf(rm, __shfl_xor(rm, 32, 64));
      float mn = fmaxf(m_r, rm);
      float alpha = exp2a(m_r - mn);
#pragma unroll
      for (int nf = 0; nf < 5; ++nf)
#pragma unroll
        for (int r = 0; r < 4; ++r) oa[nf][r] *= alpha;
      m_r = mn;
    }
#pragma unroll
    for (int nf = 0; nf < 2; ++nf)
#pragma unroll
      for (int r = 0; r < 4; ++r) stA[nf][r] = exp2a(stA[nf][r] - m_r);
#pragma unroll
    for (int nf = 0; nf < 2; ++nf) {
      uint2* dst = (uint2*)&Pl[w][(2 * nf + (g >> 1)) * 128 + lrow * 8 + (g & 1) * 4];
      *dst = make_uint2(cvt_pk2(stA[nf][0], stA[nf][1]), cvt_pk2(stA[nf][2], stA[nf][3]));
    }
    short8 pa = *(const short8*)&Pl[w][g * 128 + lrow * 8];
#pragma unroll
    for (int nf = 0; nf < 5; ++nf) {
      short8 bv = *(const short8*)&KV3[b0 + 3072 + g * 768 + (nf * 16 + lrow) * 8];
      oa[nf] = __builtin_amdgcn_mfma_f32_16x16x32_bf16(bv, pa, oa[nf], 0, 0, 0);
    }
  }

  asm volatile("s_waitcnt vmcnt(0)" ::: "memory");

  float lt = __shfl(oa[4][0], 32 + lrow, 64);
  float rcp = 1.f / lt;
  size_t obase = (size_t)(q0 + lrow) * HID + h * HD;
#pragma unroll
  for (int nf = 0; nf < 5; ++nf) {
    int d = nf * 16 + g * 4;
    if (d + 3 < HD) {
      uint2 pk = make_uint2(cvt_pk2(oa[nf][0] * rcp, oa[nf][1] * rcp),
                            cvt_pk2(oa[nf][2] * rcp, oa[nf][3] * rcp));
      *(uint2*)&o[obase + d] = pk;
    }
  }
}

// ---------------- launch ----------------
extern "C" void kernel_launch(void* const* d_in, const int* in_sizes, int n_in,
                              void* d_out, int out_size, void* d_ws, size_t ws_size,
                              hipStream_t stream) {
  (void)in_sizes; (void)n_in; (void)out_size;
  const float* hidden = (const float*)d_in[0];
  const float* cosb = (const float*)d_in[1];
  const float* sinb = (const float*)d_in[2];
  const float* ln0g = (const float*)d_in[3];
  const float* ln0b = (const float*)d_in[4];
  const float* ln1g = (const float*)d_in[5];
  const float* ln1b = (const float*)d_in[6];
  const float* wqkv = (const float*)d_in[7];
  const float* bqkv = (const float*)d_in[8];
  const float* wo = (const float*)d_in[9];
  const float* bo = (const float*)d_in[10];
  const float* w0 = (const float*)d_in[11];
  const float* b0 = (const float*)d_in[12];
  const float* w1 = (const float*)d_in[13];
  const float* b1 = (const float*)d_in[14];

  char* p = (char*)d_ws;
  auto alloc = [&](size_t n) {
    char* r = p;
    p += (n + 255) & ~(size_t)255;
    return r;
  };
  bf16* wqkv_bf = (bf16*)alloc((size_t)3 * HID * HID * 2);
  bf16* wo_bf = (bf16*)alloc((size_t)HID * HID * 2);
  bf16* fc0_bf = (bf16*)alloc((size_t)MLPP * HID * 2);
  bf16* fc1_bf = (bf16*)alloc((size_t)HID * MLPP * 2);
  bf16* ln0_bf = (bf16*)alloc((size_t)SEQ * HID * 2);
  bf16* qp = (bf16*)alloc((size_t)NHEAD * SEQ * HDP * 2);
  bf16* kp = (bf16*)alloc((size_t)NHEAD * SEQ * HDP * 2);
  bf16* vt = (bf16*)alloc((size_t)NHEAD * HDP * SEQ * 2);
  bf16* attn_bf = (bf16*)alloc((size_t)SEQ * HID * 2);
  bf16* h1b = (bf16*)alloc((size_t)SEQ * HID * 2);
  bf16* ln1_bf = (bf16*)alloc((size_t)SEQ * HID * 2);
  bf16* gelu_bf = (bf16*)alloc((size_t)SEQ * MLPP * 2);
  if ((size_t)(p - (char*)d_ws) > ws_size) return;

  dim3 blk(256);
  prep_k<<<SEQ + 1024, blk, 0, stream>>>(hidden, ln0g, ln0b, wqkv, wo, w0, w1, ln0_bf,
                                         (unsigned*)wqkv_bf, (unsigned*)wo_bf,
                                         (unsigned*)fc0_bf, (unsigned*)fc1_bf, qp, kp, vt);
  gemm_qkv<<<dim3((3 * HID / 128) * (SEQ / 128)), blk, 0, stream>>>(
      ln0_bf, wqkv_bf, bqkv, cosb, sinb, qp, kp, vt);
  flash_attn<<<dim3(768), blk, 0, stream>>>(qp, kp, vt, attn_bf);
  gemm_bf16<1, 64><<<dim3((HID / 64) * (SEQ / 128)), blk, 0, stream>>>(
      attn_bf, wo_bf, bo, HID, hidden, nullptr, nullptr, h1b, SEQ, HID, HID);
  ln_bf_k<<<SEQ, blk, 0, stream>>>(h1b, ln1g, ln1b, ln1_bf);
  gemm_bf16<2, 64><<<dim3((MLPP / 64) * (SEQ / 128)), blk, 0, stream>>>(
      ln1_bf, fc0_bf, b0, MLPD, nullptr, nullptr, nullptr, gelu_bf, SEQ, MLPP, HID);
  gemm_bf16<3, 64><<<dim3((HID / 64) * (SEQ / 128)), blk, 0, stream>>>(
      gelu_bf, fc1_bf, b1, HID, nullptr, h1b, (float*)d_out, nullptr, SEQ, HID, MLPP);
}